// Round 7
// baseline (629.095 us; speedup 1.0000x reference)
//
#include <hip/hip_runtime.h>
#include <stdint.h>

#pragma clang fp contract(off)   // match numpy: no FMA fusion in decode/IoU math

static constexpr int TOPK  = 5000;
static constexpr int KEEPK = 750;
static constexpr int MPAD  = 65536;   // >= N (33600), power of 2
static constexpr int NBLK  = (TOPK + 63) / 64;   // 79
static constexpr int KROW  = NBLK * 64;          // 5056 (padded mask row)
static constexpr float TH  = 0.3f;    // strict '>' everywhere (f32 weak-typed 0.3)

__device__ __forceinline__ uint32_t key_of(float f) {
  uint32_t u = __float_as_uint(f);
  u = (u & 0x80000000u) ? ~u : (u | 0x80000000u);  // ascending-ordered uint
  return ~u;                                        // ascending key == descending float
}
__device__ __forceinline__ float val_of(uint32_t key) {
  uint32_t u = ~key;
  return (u & 0x80000000u) ? __uint_as_float(u ^ 0x80000000u) : __uint_as_float(~u);
}

// ---------------- stage 1: composite keys (score desc, index asc) ----------------
__global__ void build_keys(const float* __restrict__ cls, const float* __restrict__ obj,
                           uint64_t* __restrict__ keys, int N) {
  int b = blockIdx.y;
  int i = blockIdx.x * blockDim.x + threadIdx.x;
  if (i >= MPAD) return;
  uint64_t c = ~0ull;
  if (i < N) {
    size_t o = (size_t)b * N + i;
    float s = sqrtf(cls[o] * obj[o]);          // mul+sqrt: bit-exact vs np
    float m = (s > TH) ? s : -1.0f;            // strict > (jax weak-typed f32 0.3)
    c = ((uint64_t)key_of(m) << 32) | (uint32_t)i;
  }
  keys[(size_t)b * MPAD + i] = c;
}

// ---------------- local bitonic: sorts each 8192-chunk, alternating asc/desc ----------------
__global__ __launch_bounds__(1024) void bitonic_local_full(uint64_t* __restrict__ keys) {
  __shared__ uint64_t sh[8192];
  int base = blockIdx.x * 8192;
  uint64_t* a = keys + (size_t)blockIdx.y * MPAD + base;
  for (int t = threadIdx.x; t < 8192; t += 1024) sh[t] = a[t];
  __syncthreads();
  for (int k = 2; k <= 8192; k <<= 1) {
    for (int j = k >> 1; j > 0; j >>= 1) {
      for (int t = threadIdx.x; t < 4096; t += 1024) {
        int i = ((t & ~(j - 1)) << 1) | (t & (j - 1));
        int l = i | j;
        bool asc = (((base + i) & k) == 0);
        uint64_t x = sh[i], y = sh[l];
        if ((x > y) == asc) { sh[i] = y; sh[l] = x; }
      }
      __syncthreads();
    }
  }
  for (int t = threadIdx.x; t < 8192; t += 1024) a[t] = sh[t];
}

// ---------------- merge-prune: keep smallest 8192 of (asc, desc) chunk pair ----------------
__global__ __launch_bounds__(1024) void merge_prune(const uint64_t* __restrict__ src,
                                                    uint64_t* __restrict__ dst) {
  __shared__ uint64_t sh[8192];
  int m = blockIdx.x, b = blockIdx.y;
  const uint64_t* A  = src + ((size_t)b * gridDim.x * 2 + 2 * m) * 8192;
  const uint64_t* Bp = A + 8192;
  for (int t = threadIdx.x; t < 8192; t += 1024) {
    uint64_t x = A[t], y = Bp[t];
    sh[t] = x < y ? x : y;
  }
  __syncthreads();
  bool asc = ((m & 1) == 0);
  for (int j = 4096; j > 0; j >>= 1) {
    for (int t = threadIdx.x; t < 4096; t += 1024) {
      int i = ((t & ~(j - 1)) << 1) | (t & (j - 1));
      int l = i | j;
      uint64_t x = sh[i], y = sh[l];
      if ((x > y) == asc) { sh[i] = y; sh[l] = x; }
    }
    __syncthreads();
  }
  uint64_t* D = dst + ((size_t)b * gridDim.x + m) * 8192;
  for (int t = threadIdx.x; t < 8192; t += 1024) D[t] = sh[t];
}

// ---------------- stage 2: gather top-5000, decode boxes+kps ----------------
__global__ void gather_decode(const uint64_t* __restrict__ keys,
                              const float* __restrict__ bbox, const float* __restrict__ kps,
                              const float* __restrict__ priors,
                              float* __restrict__ dets, float* __restrict__ tscore, int N) {
  int b = blockIdx.y;
  int r = blockIdx.x * blockDim.x + threadIdx.x;
  if (r >= TOPK) return;
  uint64_t c = keys[(size_t)b * 8192 + r];
  uint32_t idx = (uint32_t)c;
  float score = val_of((uint32_t)(c >> 32));
  float4 pr = ((const float4*)priors)[idx];
  const float* bb = bbox + ((size_t)b * N + idx) * 4;
  float cx = pr.x + bb[0] * pr.z;
  float cy = pr.y + bb[1] * pr.w;
  float w = pr.z * expf(bb[2]);
  float h = pr.w * expf(bb[3]);
  float x1 = cx - w * 0.5f, y1 = cy - h * 0.5f;
  float* d = dets + ((size_t)b * TOPK + r) * 16;
  d[0] = x1; d[1] = y1; d[2] = x1 + w; d[3] = y1 + h;
  const float* kp = kps + ((size_t)b * N + idx) * 10;
#pragma unroll
  for (int q = 0; q < 5; ++q) {
    d[4 + 2 * q] = pr.x + kp[2 * q] * pr.z;
    d[5 + 2 * q] = pr.y + kp[2 * q + 1] * pr.w;
  }
  d[14] = score;
  tscore[(size_t)b * TOPK + r] = score;
}

// ---------------- stage 3: NMS bitmask, transposed + diag kill-words ----------------
__global__ __launch_bounds__(64) void nms_mask(const float* __restrict__ dets,
                                               uint64_t* __restrict__ tmask,
                                               uint64_t* __restrict__ diag) {
  int sbk = blockIdx.x, tbk = blockIdx.y, b = blockIdx.z;
  if (tbk < sbk) return;
  __shared__ float4 tbox[64];
  int t = threadIdx.x;
  int j0 = tbk * 64;
  {
    int j = j0 + t;
    if (j < TOPK) {
      const float* dj = dets + ((size_t)b * TOPK + j) * 16;
      tbox[t] = make_float4(dj[0], dj[1], dj[2], dj[3]);
    } else tbox[t] = make_float4(0.f, 0.f, 0.f, 0.f);
  }
  __syncthreads();
  int i = sbk * 64 + t;
  uint64_t bits = 0;
  if (i < TOPK) {
    const float* di = dets + ((size_t)b * TOPK + i) * 16;
    float ix1 = di[0], iy1 = di[1], ix2 = di[2], iy2 = di[3];
    float iar = fmaxf(ix2 - ix1, 0.f) * fmaxf(iy2 - iy1, 0.f);
    int jmax = min(64, TOPK - j0);
    for (int u = 0; u < jmax; ++u) {
      int j = j0 + u;
      if (j <= i) continue;
      float4 bx = tbox[u];
      float xx1 = fmaxf(ix1, bx.x), yy1 = fmaxf(iy1, bx.y);
      float xx2 = fminf(ix2, bx.z), yy2 = fminf(iy2, bx.w);
      float ww = fmaxf(xx2 - xx1, 0.f), hh = fmaxf(yy2 - yy1, 0.f);
      float inter = ww * hh;
      float jar = fmaxf(bx.z - bx.x, 0.f) * fmaxf(bx.w - bx.y, 0.f);
      float iou = inter / (iar + jar - inter + 1e-12f);
      if (iou > TH) bits |= (1ull << u);       // strict > (f32 0.3)
    }
  }
  // in-chunk kill words for the scalar closure (source-major, bits only > t)
  if (sbk == tbk) diag[((size_t)b * NBLK + sbk) * 64 + t] = bits;
  // transpose: word for target u = ballot over source lanes of bit u
  uint64_t tw = 0;
#pragma unroll
  for (int u = 0; u < 64; ++u) {
    uint64_t bal = __ballot((bits >> u) & 1ull);
    if (t == u) tw = bal;
  }
  tmask[((size_t)b * NBLK + tbk) * KROW + (size_t)(sbk * 64 + t)] = tw;
}

// ---------------- stage 4+5: 4-wave register-prefetch scan + fused top-750 emit ----------------
// Round-6 lesson: single-wave global_load_lds staging costs ~500cyc/instr (no per-wave
// DMA pipelining) and dominated rounds 4-6. This version holds mask rows in REGISTERS:
// each wave owns rows r==wid (mod 4) of the current chunk in a statically-indexed
// 20-slot array (plain coalesced loads, issued 20-deep, 1 chunk ahead). Unconditional
// load/AND; garbage slots are masked by s_alive==0 (pre-zeroed). Wave 0 runs the
// branchless SALU closure on diag kill-words prefetched in registers.
__global__ __launch_bounds__(256) void nms_scan_emit(const uint64_t* __restrict__ tmask,
                                                     const uint64_t* __restrict__ diag,
                                                     const float* __restrict__ tscore,
                                                     const float* __restrict__ dets,
                                                     float* __restrict__ out, int B) {
  __shared__ uint64_t s_part[4][64];
  __shared__ uint64_t s_alive[96];
  __shared__ int s_pref[NBLK + 1];
  int b = blockIdx.x;
  int tid = threadIdx.x;
  int wid = tid >> 6, lane = tid & 63;
  const uint64_t* mb = tmask + (size_t)b * NBLK * KROW;
  const uint64_t* db = diag + (size_t)b * NBLK * 64;
  const float* sb = tscore + (size_t)b * TOPK;

  if (tid < 96) s_alive[tid] = 0;

  // register row cache: slot k holds row (k*4+wid) of the CURRENT chunk
  uint64_t rows[20];
#pragma unroll
  for (int k = 0; k < 20; ++k) rows[k] = 0;      // chunk 0 has no prior rows

  // prefetch chunk 0's diag kill-word and scores (registers, rotated per chunk)
  uint64_t dreg_n = db[lane];
  float scr_n = sb[lane];
  uint64_t dreg_c; float scr_c;
  __syncthreads();                                // s_alive zeroing visible

  for (int c = 0; c < NBLK; ++c) {
    // phase A: partial suppression for this wave's rows (statically unrolled;
    // slots with row >= c contribute 0 via s_alive). s_alive reads broadcast.
    uint64_t partial = 0;
#pragma unroll
    for (int k = 0; k < 20; ++k)
      partial |= rows[k] & s_alive[k * 4 + wid];
    s_part[wid][lane] = partial;

    // rotate prefetched closure operands (wait lands here; issued ~1 chunk ago)
    dreg_c = dreg_n;
    scr_c = scr_n;

    // phase B: issue next chunk's loads (land during closure + next phase A)
    {
      int tn = min(c + 1, NBLK - 1);              // clamped: garbage ok, masked later
      const uint64_t* rowsrc = mb + (size_t)tn * KROW;
#pragma unroll
      for (int k = 0; k < 20; ++k)
        rows[k] = rowsrc[(size_t)((k * 4 + wid) * 64 + lane)];
      dreg_n = db[(size_t)tn * 64 + lane];
      scr_n = sb[(size_t)tn * 64 + lane];         // beyond TOPK -> pad (guarded by p<TOPK)
    }
    __syncthreads();                              // s_part visible

    if (wid == 0) {
      uint64_t sup64 = s_part[0][lane] | s_part[1][lane] | s_part[2][lane] | s_part[3][lane];
      int p = c * 64 + lane;
      bool sup = (sup64 != 0) || !(p < TOPK && scr_c > TH);
      uint64_t avail = __ballot(!sup);
      uint32_t dlo = (uint32_t)dreg_c, dhi = (uint32_t)(dreg_c >> 32);
      uint64_t alive = 0;
#pragma unroll
      for (int t = 0; t < 64; ++t) {              // branchless scalar greedy closure
        uint64_t kill = ((uint64_t)__builtin_amdgcn_readlane(dhi, t) << 32)
                      | (uint64_t)__builtin_amdgcn_readlane(dlo, t);
        uint64_t take = (avail >> t) & 1ull;
        alive |= take << t;
        avail &= ~(kill & (0ull - take));
      }
      if (lane == 0) s_alive[c] = alive;
    }
    __syncthreads();                              // s_alive[c] visible
  }

  // prefix sums of kept counts per chunk
  if (tid == 0) {
    int run = 0;
    for (int cb = 0; cb < NBLK; ++cb) { s_pref[cb] = run; run += __popcll(s_alive[cb]); }
    s_pref[NBLK] = run;
  }
  __syncthreads();
  int K = s_pref[NBLK];

  // top-750 of where(keep, score, -1) == [kept in position order] ++ [not-kept in
  // position order]  (tscore already desc with index-asc ties; -1 ties -> index asc)
  for (int cb = wid; cb < NBLK; cb += 4) {
    int p = cb * 64 + lane;
    if (p >= TOPK) continue;
    uint64_t aw = s_alive[cb];
    int kept = (int)((aw >> lane) & 1ull);
    int within = __popcll(aw & ((1ull << lane) - 1ull));
    int rank = s_pref[cb] + within;                          // kept rank
    int slot = kept ? rank : (K + (p - s_pref[cb] - within)); // filler after all kept
    if (slot < KEEPK) {
      const float* d = dets + ((size_t)b * TOPK + p) * 16;
      float* o = out + ((size_t)b * KEEPK + slot) * 15;
#pragma unroll
      for (int ccol = 0; ccol < 15; ++ccol) o[ccol] = d[ccol];
      out[(size_t)B * KEEPK * 15 + (size_t)b * KEEPK + slot] = kept ? 1.0f : 0.0f;
    }
  }
}

extern "C" void kernel_launch(void* const* d_in, const int* in_sizes, int n_in,
                              void* d_out, int out_size, void* d_ws, size_t ws_size,
                              hipStream_t stream) {
  const float* cls    = (const float*)d_in[0];
  const float* obj    = (const float*)d_in[1];
  const float* bbox   = (const float*)d_in[2];
  const float* kps    = (const float*)d_in[3];
  const float* priors = (const float*)d_in[4];
  int N = in_sizes[4] / 4;
  int B = in_sizes[0] / N;
  if (N > MPAD) return;

  char* ws = (char*)d_ws;
  size_t off = 0;
  auto alloc = [&](size_t bytes) -> void* {
    void* p = ws + off;
    off += (bytes + 255) & ~(size_t)255;
    return p;
  };
  uint64_t* keys1  = (uint64_t*)alloc((size_t)B * MPAD * 8);
  float*    dets   = (float*)   alloc((size_t)B * TOPK * 16 * 4);
  float*    tscore = (float*)   alloc((size_t)B * TOPK * 4 + 4096);      // + prefetch pad
  uint64_t* diag   = (uint64_t*)alloc((size_t)B * NBLK * 64 * 8 + 4096); // + prefetch pad
  uint64_t* tmask  = (uint64_t*)alloc((size_t)B * NBLK * KROW * 8 + 4096);
  if (off > ws_size) return;  // fail visibly rather than corrupt
  // merge buffers alias tmask (lifetimes disjoint: sort completes before nms_mask)
  uint64_t* keys2 = tmask;                       // B * 4 * 8192
  uint64_t* keys3 = keys2 + (size_t)B * 4 * 8192;
  uint64_t* keys4 = keys3 + (size_t)B * 2 * 8192;

  build_keys<<<dim3((MPAD + 255) / 256, B), 256, 0, stream>>>(cls, obj, keys1, N);
  bitonic_local_full<<<dim3(MPAD / 8192, B), 1024, 0, stream>>>(keys1);
  merge_prune<<<dim3(4, B), 1024, 0, stream>>>(keys1, keys2);
  merge_prune<<<dim3(2, B), 1024, 0, stream>>>(keys2, keys3);
  merge_prune<<<dim3(1, B), 1024, 0, stream>>>(keys3, keys4);
  gather_decode<<<dim3((TOPK + 255) / 256, B), 256, 0, stream>>>(keys4, bbox, kps, priors,
                                                                 dets, tscore, N);
  nms_mask<<<dim3(NBLK, NBLK, B), 64, 0, stream>>>(dets, tmask, diag);
  nms_scan_emit<<<B, 256, 0, stream>>>(tmask, diag, tscore, dets, (float*)d_out, B);
}

// Round 8
// 567.817 us; speedup vs baseline: 1.1079x; 1.1079x over previous
//
#include <hip/hip_runtime.h>
#include <stdint.h>

#pragma clang fp contract(off)   // match numpy: no FMA fusion in decode/IoU math

static constexpr int TOPK  = 5000;
static constexpr int KEEPK = 750;
static constexpr int MPAD  = 65536;   // >= N (33600), power of 2
static constexpr int NBLK  = (TOPK + 63) / 64;   // 79
static constexpr int KROW  = NBLK * 64;          // 5056 (padded mask row)
static constexpr float TH  = 0.3f;    // strict '>' everywhere (f32 weak-typed 0.3)

__device__ __forceinline__ uint32_t key_of(float f) {
  uint32_t u = __float_as_uint(f);
  u = (u & 0x80000000u) ? ~u : (u | 0x80000000u);  // ascending-ordered uint
  return ~u;                                        // ascending key == descending float
}
__device__ __forceinline__ float val_of(uint32_t key) {
  uint32_t u = ~key;
  return (u & 0x80000000u) ? __uint_as_float(u ^ 0x80000000u) : __uint_as_float(~u);
}

// ---------------- stage 1: composite keys (score desc, index asc) ----------------
__global__ void build_keys(const float* __restrict__ cls, const float* __restrict__ obj,
                           uint64_t* __restrict__ keys, int N) {
  int b = blockIdx.y;
  int i = blockIdx.x * blockDim.x + threadIdx.x;
  if (i >= MPAD) return;
  uint64_t c = ~0ull;
  if (i < N) {
    size_t o = (size_t)b * N + i;
    float s = sqrtf(cls[o] * obj[o]);          // mul+sqrt: bit-exact vs np
    float m = (s > TH) ? s : -1.0f;            // strict > (jax weak-typed f32 0.3)
    c = ((uint64_t)key_of(m) << 32) | (uint32_t)i;
  }
  keys[(size_t)b * MPAD + i] = c;
}

// ---------------- local bitonic: sorts each 8192-chunk, alternating asc/desc ----------------
__global__ __launch_bounds__(1024) void bitonic_local_full(uint64_t* __restrict__ keys) {
  __shared__ uint64_t sh[8192];
  int base = blockIdx.x * 8192;
  uint64_t* a = keys + (size_t)blockIdx.y * MPAD + base;
  for (int t = threadIdx.x; t < 8192; t += 1024) sh[t] = a[t];
  __syncthreads();
  for (int k = 2; k <= 8192; k <<= 1) {
    for (int j = k >> 1; j > 0; j >>= 1) {
      for (int t = threadIdx.x; t < 4096; t += 1024) {
        int i = ((t & ~(j - 1)) << 1) | (t & (j - 1));
        int l = i | j;
        bool asc = (((base + i) & k) == 0);
        uint64_t x = sh[i], y = sh[l];
        if ((x > y) == asc) { sh[i] = y; sh[l] = x; }
      }
      __syncthreads();
    }
  }
  for (int t = threadIdx.x; t < 8192; t += 1024) a[t] = sh[t];
}

// ---------------- merge-prune: keep smallest 8192 of (asc, desc) chunk pair ----------------
__global__ __launch_bounds__(1024) void merge_prune(const uint64_t* __restrict__ src,
                                                    uint64_t* __restrict__ dst) {
  __shared__ uint64_t sh[8192];
  int m = blockIdx.x, b = blockIdx.y;
  const uint64_t* A  = src + ((size_t)b * gridDim.x * 2 + 2 * m) * 8192;
  const uint64_t* Bp = A + 8192;
  for (int t = threadIdx.x; t < 8192; t += 1024) {
    uint64_t x = A[t], y = Bp[t];
    sh[t] = x < y ? x : y;
  }
  __syncthreads();
  bool asc = ((m & 1) == 0);
  for (int j = 4096; j > 0; j >>= 1) {
    for (int t = threadIdx.x; t < 4096; t += 1024) {
      int i = ((t & ~(j - 1)) << 1) | (t & (j - 1));
      int l = i | j;
      uint64_t x = sh[i], y = sh[l];
      if ((x > y) == asc) { sh[i] = y; sh[l] = x; }
    }
    __syncthreads();
  }
  uint64_t* D = dst + ((size_t)b * gridDim.x + m) * 8192;
  for (int t = threadIdx.x; t < 8192; t += 1024) D[t] = sh[t];
}

// ---------------- stage 2: gather top-5000, decode boxes+kps ----------------
__global__ void gather_decode(const uint64_t* __restrict__ keys,
                              const float* __restrict__ bbox, const float* __restrict__ kps,
                              const float* __restrict__ priors,
                              float* __restrict__ dets, float* __restrict__ tscore, int N) {
  int b = blockIdx.y;
  int r = blockIdx.x * blockDim.x + threadIdx.x;
  if (r >= TOPK) return;
  uint64_t c = keys[(size_t)b * 8192 + r];
  uint32_t idx = (uint32_t)c;
  float score = val_of((uint32_t)(c >> 32));
  float4 pr = ((const float4*)priors)[idx];
  const float* bb = bbox + ((size_t)b * N + idx) * 4;
  float cx = pr.x + bb[0] * pr.z;
  float cy = pr.y + bb[1] * pr.w;
  float w = pr.z * expf(bb[2]);
  float h = pr.w * expf(bb[3]);
  float x1 = cx - w * 0.5f, y1 = cy - h * 0.5f;
  float* d = dets + ((size_t)b * TOPK + r) * 16;
  d[0] = x1; d[1] = y1; d[2] = x1 + w; d[3] = y1 + h;
  const float* kp = kps + ((size_t)b * N + idx) * 10;
#pragma unroll
  for (int q = 0; q < 5; ++q) {
    d[4 + 2 * q] = pr.x + kp[2 * q] * pr.z;
    d[5 + 2 * q] = pr.y + kp[2 * q + 1] * pr.w;
  }
  d[14] = score;
  tscore[(size_t)b * TOPK + r] = score;
}

// ---------------- stage 3: NMS bitmask, transposed + diag kill-words ----------------
__global__ __launch_bounds__(64) void nms_mask(const float* __restrict__ dets,
                                               uint64_t* __restrict__ tmask,
                                               uint64_t* __restrict__ diag) {
  int sbk = blockIdx.x, tbk = blockIdx.y, b = blockIdx.z;
  if (tbk < sbk) return;
  __shared__ float4 tbox[64];
  int t = threadIdx.x;
  int j0 = tbk * 64;
  {
    int j = j0 + t;
    if (j < TOPK) {
      const float* dj = dets + ((size_t)b * TOPK + j) * 16;
      tbox[t] = make_float4(dj[0], dj[1], dj[2], dj[3]);
    } else tbox[t] = make_float4(0.f, 0.f, 0.f, 0.f);
  }
  __syncthreads();
  int i = sbk * 64 + t;
  uint64_t bits = 0;
  if (i < TOPK) {
    const float* di = dets + ((size_t)b * TOPK + i) * 16;
    float ix1 = di[0], iy1 = di[1], ix2 = di[2], iy2 = di[3];
    float iar = fmaxf(ix2 - ix1, 0.f) * fmaxf(iy2 - iy1, 0.f);
    int jmax = min(64, TOPK - j0);
    for (int u = 0; u < jmax; ++u) {
      int j = j0 + u;
      if (j <= i) continue;
      float4 bx = tbox[u];
      float xx1 = fmaxf(ix1, bx.x), yy1 = fmaxf(iy1, bx.y);
      float xx2 = fminf(ix2, bx.z), yy2 = fminf(iy2, bx.w);
      float ww = fmaxf(xx2 - xx1, 0.f), hh = fmaxf(yy2 - yy1, 0.f);
      float inter = ww * hh;
      float jar = fmaxf(bx.z - bx.x, 0.f) * fmaxf(bx.w - bx.y, 0.f);
      float iou = inter / (iar + jar - inter + 1e-12f);
      if (iou > TH) bits |= (1ull << u);       // strict > (f32 0.3)
    }
  }
  // in-chunk kill words for the scalar closure (source-major, bits only > t)
  if (sbk == tbk) diag[((size_t)b * NBLK + sbk) * 64 + t] = bits;
  // transpose: word for target u = ballot over source lanes of bit u
  uint64_t tw = 0;
#pragma unroll
  for (int u = 0; u < 64; ++u) {
    uint64_t bal = __ballot((bits >> u) & 1ull);
    if (t == u) tw = bal;
  }
  tmask[((size_t)b * NBLK + tbk) * KROW + (size_t)(sbk * 64 + t)] = tw;
}

// ---------------- stage 4+5: raw-barrier pipelined scan + fused top-750 emit ----------------
// Round-7 lesson: __syncthreads == s_waitcnt vmcnt(0)+s_barrier, which DRAINED the
// 20 just-issued loads every chunk (~10k cyc/chunk invariant across r4-r7). Here:
// raw s_barrier + lgkmcnt(0) only -> register loads issued in iter c are first
// waited on (per-register vmcnt) at phase A of iter c+1, with barrier+closure+barrier
// of slack. Closure = scalar ffs loop over TAKEN items only (avail is SGPR-uniform).
__global__ __launch_bounds__(256) void nms_scan_emit(const uint64_t* __restrict__ tmask,
                                                     const uint64_t* __restrict__ diag,
                                                     const float* __restrict__ tscore,
                                                     const float* __restrict__ dets,
                                                     float* __restrict__ out, int B) {
  __shared__ uint64_t s_part[4][64];
  __shared__ uint64_t s_alive[96];
  __shared__ int s_pref[NBLK + 1];
  int b = blockIdx.x;
  int tid = threadIdx.x;
  int wid = tid >> 6, lane = tid & 63;
  const uint64_t* mb = tmask + (size_t)b * NBLK * KROW;
  const uint64_t* db = diag + (size_t)b * NBLK * 64;
  const float* sb = tscore + (size_t)b * TOPK;

  if (tid < 96) s_alive[tid] = 0;

  // register row cache: slot k holds row (k*4+wid) of the CURRENT chunk
  uint64_t rows[20];
#pragma unroll
  for (int k = 0; k < 20; ++k) rows[k] = 0;      // chunk 0 has no prior rows

  // prefetch chunk 0's diag kill-word and scores (registers, rotated per chunk)
  uint64_t dreg_n = db[lane];
  float scr_n = sb[lane];
  uint64_t dreg_c; float scr_c;
  __syncthreads();                                // s_alive zeroing visible (once)

  for (int c = 0; c < NBLK; ++c) {
    // phase A: partial suppression for this wave's rows. rows[] were loaded in
    // iter c-1 phase B; first read here auto-waits the right vmcnt. Slots with
    // row >= c contribute 0 via s_alive (pre-zeroed). s_alive reads broadcast.
    uint64_t partial = 0;
#pragma unroll
    for (int k = 0; k < 20; ++k)
      partial |= rows[k] & s_alive[k * 4 + wid];
    s_part[wid][lane] = partial;

    dreg_c = dreg_n;                              // rotate prefetched operands
    scr_c = scr_n;

    // phase B: issue next chunk's loads; they stay IN FLIGHT across the raw
    // barriers below (no vmcnt drain) until phase A of iter c+1.
    {
      int tn = min(c + 1, NBLK - 1);
      const uint64_t* rowsrc = mb + (size_t)tn * KROW;
#pragma unroll
      for (int k = 0; k < 20; ++k) {
        int r = k * 4 + wid;                      // wave-uniform guard: only rows
        if (r <= tn)                              // the gather can ever use
          rows[k] = rowsrc[(size_t)(r * 64 + lane)];
      }
      dreg_n = db[(size_t)tn * 64 + lane];
      scr_n = sb[(size_t)tn * 64 + lane];
    }
    asm volatile("s_waitcnt lgkmcnt(0)" ::: "memory");  // s_part visible
    __builtin_amdgcn_s_barrier();

    if (wid == 0) {
      uint64_t sup64 = s_part[0][lane] | s_part[1][lane] | s_part[2][lane] | s_part[3][lane];
      int p = c * 64 + lane;
      bool sup = (sup64 != 0) || !(p < TOPK && scr_c > TH);
      uint64_t avail = __ballot(!sup);            // uniform (SGPR) candidate set
      uint32_t dlo = (uint32_t)dreg_c, dhi = (uint32_t)(dreg_c >> 32);
      uint64_t alive = 0;
      while (avail) {                             // scalar greedy closure:
        int t = __ffsll((unsigned long long)avail) - 1;  // only TAKEN items cost
        uint64_t kill = ((uint64_t)__builtin_amdgcn_readlane(dhi, t) << 32)
                      | (uint64_t)__builtin_amdgcn_readlane(dlo, t);
        alive |= 1ull << t;
        avail &= ~(kill | (1ull << t));
      }
      if (lane == 0) s_alive[c] = alive;
      asm volatile("s_waitcnt lgkmcnt(0)" ::: "memory");  // s_alive[c] visible
    }
    __builtin_amdgcn_s_barrier();
  }

  __syncthreads();                                // full drain once before emit

  // prefix sums of kept counts per chunk
  if (tid == 0) {
    int run = 0;
    for (int cb = 0; cb < NBLK; ++cb) { s_pref[cb] = run; run += __popcll(s_alive[cb]); }
    s_pref[NBLK] = run;
  }
  __syncthreads();
  int K = s_pref[NBLK];

  // top-750 of where(keep, score, -1) == [kept in position order] ++ [not-kept in
  // position order]  (tscore already desc with index-asc ties; -1 ties -> index asc)
  for (int cb = wid; cb < NBLK; cb += 4) {
    int p = cb * 64 + lane;
    if (p >= TOPK) continue;
    uint64_t aw = s_alive[cb];
    int kept = (int)((aw >> lane) & 1ull);
    int within = __popcll(aw & ((1ull << lane) - 1ull));
    int rank = s_pref[cb] + within;                          // kept rank
    int slot = kept ? rank : (K + (p - s_pref[cb] - within)); // filler after all kept
    if (slot < KEEPK) {
      const float* d = dets + ((size_t)b * TOPK + p) * 16;
      float* o = out + ((size_t)b * KEEPK + slot) * 15;
#pragma unroll
      for (int ccol = 0; ccol < 15; ++ccol) o[ccol] = d[ccol];
      out[(size_t)B * KEEPK * 15 + (size_t)b * KEEPK + slot] = kept ? 1.0f : 0.0f;
    }
  }
}

extern "C" void kernel_launch(void* const* d_in, const int* in_sizes, int n_in,
                              void* d_out, int out_size, void* d_ws, size_t ws_size,
                              hipStream_t stream) {
  const float* cls    = (const float*)d_in[0];
  const float* obj    = (const float*)d_in[1];
  const float* bbox   = (const float*)d_in[2];
  const float* kps    = (const float*)d_in[3];
  const float* priors = (const float*)d_in[4];
  int N = in_sizes[4] / 4;
  int B = in_sizes[0] / N;
  if (N > MPAD) return;

  char* ws = (char*)d_ws;
  size_t off = 0;
  auto alloc = [&](size_t bytes) -> void* {
    void* p = ws + off;
    off += (bytes + 255) & ~(size_t)255;
    return p;
  };
  uint64_t* keys1  = (uint64_t*)alloc((size_t)B * MPAD * 8);
  float*    dets   = (float*)   alloc((size_t)B * TOPK * 16 * 4);
  float*    tscore = (float*)   alloc((size_t)B * TOPK * 4 + 4096);      // + prefetch pad
  uint64_t* diag   = (uint64_t*)alloc((size_t)B * NBLK * 64 * 8 + 4096); // + prefetch pad
  uint64_t* tmask  = (uint64_t*)alloc((size_t)B * NBLK * KROW * 8 + 4096);
  if (off > ws_size) return;  // fail visibly rather than corrupt
  // merge buffers alias tmask (lifetimes disjoint: sort completes before nms_mask)
  uint64_t* keys2 = tmask;                       // B * 4 * 8192
  uint64_t* keys3 = keys2 + (size_t)B * 4 * 8192;
  uint64_t* keys4 = keys3 + (size_t)B * 2 * 8192;

  build_keys<<<dim3((MPAD + 255) / 256, B), 256, 0, stream>>>(cls, obj, keys1, N);
  bitonic_local_full<<<dim3(MPAD / 8192, B), 1024, 0, stream>>>(keys1);
  merge_prune<<<dim3(4, B), 1024, 0, stream>>>(keys1, keys2);
  merge_prune<<<dim3(2, B), 1024, 0, stream>>>(keys2, keys3);
  merge_prune<<<dim3(1, B), 1024, 0, stream>>>(keys3, keys4);
  gather_decode<<<dim3((TOPK + 255) / 256, B), 256, 0, stream>>>(keys4, bbox, kps, priors,
                                                                 dets, tscore, N);
  nms_mask<<<dim3(NBLK, NBLK, B), 64, 0, stream>>>(dets, tmask, diag);
  nms_scan_emit<<<B, 256, 0, stream>>>(tmask, diag, tscore, dets, (float*)d_out, B);
}

// Round 9
// 377.521 us; speedup vs baseline: 1.6664x; 1.5041x over previous
//
#include <hip/hip_runtime.h>
#include <stdint.h>

#pragma clang fp contract(off)   // match numpy: no FMA fusion in decode/IoU math

static constexpr int TOPK  = 5000;
static constexpr int KEEPK = 750;
static constexpr int MPAD  = 65536;   // >= N (33600), power of 2
static constexpr int NBLK  = (TOPK + 63) / 64;   // 79
static constexpr int KROW  = NBLK * 64;          // 5056 (padded mask row)
static constexpr float TH  = 0.3f;    // strict '>' everywhere (f32 weak-typed 0.3)

__device__ __forceinline__ uint32_t key_of(float f) {
  uint32_t u = __float_as_uint(f);
  u = (u & 0x80000000u) ? ~u : (u | 0x80000000u);  // ascending-ordered uint
  return ~u;                                        // ascending key == descending float
}
__device__ __forceinline__ float val_of(uint32_t key) {
  uint32_t u = ~key;
  return (u & 0x80000000u) ? __uint_as_float(u ^ 0x80000000u) : __uint_as_float(~u);
}

// ---------------- stage 1: composite keys (score desc, index asc) ----------------
__global__ void build_keys(const float* __restrict__ cls, const float* __restrict__ obj,
                           uint64_t* __restrict__ keys, int N) {
  int b = blockIdx.y;
  int i = blockIdx.x * blockDim.x + threadIdx.x;
  if (i >= MPAD) return;
  uint64_t c = ~0ull;
  if (i < N) {
    size_t o = (size_t)b * N + i;
    float s = sqrtf(cls[o] * obj[o]);          // mul+sqrt: bit-exact vs np
    float m = (s > TH) ? s : -1.0f;            // strict > (jax weak-typed f32 0.3)
    c = ((uint64_t)key_of(m) << 32) | (uint32_t)i;
  }
  keys[(size_t)b * MPAD + i] = c;
}

// ---------------- local bitonic: sorts each 8192-chunk, alternating asc/desc ----------------
__global__ __launch_bounds__(1024) void bitonic_local_full(uint64_t* __restrict__ keys) {
  __shared__ uint64_t sh[8192];
  int base = blockIdx.x * 8192;
  uint64_t* a = keys + (size_t)blockIdx.y * MPAD + base;
  for (int t = threadIdx.x; t < 8192; t += 1024) sh[t] = a[t];
  __syncthreads();
  for (int k = 2; k <= 8192; k <<= 1) {
    for (int j = k >> 1; j > 0; j >>= 1) {
      for (int t = threadIdx.x; t < 4096; t += 1024) {
        int i = ((t & ~(j - 1)) << 1) | (t & (j - 1));
        int l = i | j;
        bool asc = (((base + i) & k) == 0);
        uint64_t x = sh[i], y = sh[l];
        if ((x > y) == asc) { sh[i] = y; sh[l] = x; }
      }
      __syncthreads();
    }
  }
  for (int t = threadIdx.x; t < 8192; t += 1024) a[t] = sh[t];
}

// ---------------- merge-prune: keep smallest 8192 of (asc, desc) chunk pair ----------------
__global__ __launch_bounds__(1024) void merge_prune(const uint64_t* __restrict__ src,
                                                    uint64_t* __restrict__ dst) {
  __shared__ uint64_t sh[8192];
  int m = blockIdx.x, b = blockIdx.y;
  const uint64_t* A  = src + ((size_t)b * gridDim.x * 2 + 2 * m) * 8192;
  const uint64_t* Bp = A + 8192;
  for (int t = threadIdx.x; t < 8192; t += 1024) {
    uint64_t x = A[t], y = Bp[t];
    sh[t] = x < y ? x : y;
  }
  __syncthreads();
  bool asc = ((m & 1) == 0);
  for (int j = 4096; j > 0; j >>= 1) {
    for (int t = threadIdx.x; t < 4096; t += 1024) {
      int i = ((t & ~(j - 1)) << 1) | (t & (j - 1));
      int l = i | j;
      uint64_t x = sh[i], y = sh[l];
      if ((x > y) == asc) { sh[i] = y; sh[l] = x; }
    }
    __syncthreads();
  }
  uint64_t* D = dst + ((size_t)b * gridDim.x + m) * 8192;
  for (int t = threadIdx.x; t < 8192; t += 1024) D[t] = sh[t];
}

// ---------------- stage 2: gather top-5000, decode boxes+kps ----------------
__global__ void gather_decode(const uint64_t* __restrict__ keys,
                              const float* __restrict__ bbox, const float* __restrict__ kps,
                              const float* __restrict__ priors,
                              float* __restrict__ dets, float* __restrict__ tscore, int N) {
  int b = blockIdx.y;
  int r = blockIdx.x * blockDim.x + threadIdx.x;
  if (r >= TOPK) return;
  uint64_t c = keys[(size_t)b * 8192 + r];
  uint32_t idx = (uint32_t)c;
  float score = val_of((uint32_t)(c >> 32));
  float4 pr = ((const float4*)priors)[idx];
  const float* bb = bbox + ((size_t)b * N + idx) * 4;
  float cx = pr.x + bb[0] * pr.z;
  float cy = pr.y + bb[1] * pr.w;
  float w = pr.z * expf(bb[2]);
  float h = pr.w * expf(bb[3]);
  float x1 = cx - w * 0.5f, y1 = cy - h * 0.5f;
  float* d = dets + ((size_t)b * TOPK + r) * 16;
  d[0] = x1; d[1] = y1; d[2] = x1 + w; d[3] = y1 + h;
  const float* kp = kps + ((size_t)b * N + idx) * 10;
#pragma unroll
  for (int q = 0; q < 5; ++q) {
    d[4 + 2 * q] = pr.x + kp[2 * q] * pr.z;
    d[5 + 2 * q] = pr.y + kp[2 * q + 1] * pr.w;
  }
  d[14] = score;
  tscore[(size_t)b * TOPK + r] = score;
}

// ---------------- stage 3: NMS bitmask, transposed (target-major) ----------------
__global__ __launch_bounds__(64) void nms_mask(const float* __restrict__ dets,
                                               uint64_t* __restrict__ tmask) {
  int sbk = blockIdx.x, tbk = blockIdx.y, b = blockIdx.z;
  if (tbk < sbk) return;
  __shared__ float4 tbox[64];
  int t = threadIdx.x;
  int j0 = tbk * 64;
  {
    int j = j0 + t;
    if (j < TOPK) {
      const float* dj = dets + ((size_t)b * TOPK + j) * 16;
      tbox[t] = make_float4(dj[0], dj[1], dj[2], dj[3]);
    } else tbox[t] = make_float4(0.f, 0.f, 0.f, 0.f);
  }
  __syncthreads();
  int i = sbk * 64 + t;
  uint64_t bits = 0;
  if (i < TOPK) {
    const float* di = dets + ((size_t)b * TOPK + i) * 16;
    float ix1 = di[0], iy1 = di[1], ix2 = di[2], iy2 = di[3];
    float iar = fmaxf(ix2 - ix1, 0.f) * fmaxf(iy2 - iy1, 0.f);
    int jmax = min(64, TOPK - j0);
    for (int u = 0; u < jmax; ++u) {
      int j = j0 + u;
      if (j <= i) continue;
      float4 bx = tbox[u];
      float xx1 = fmaxf(ix1, bx.x), yy1 = fmaxf(iy1, bx.y);
      float xx2 = fminf(ix2, bx.z), yy2 = fminf(iy2, bx.w);
      float ww = fmaxf(xx2 - xx1, 0.f), hh = fmaxf(yy2 - yy1, 0.f);
      float inter = ww * hh;
      float jar = fmaxf(bx.z - bx.x, 0.f) * fmaxf(bx.w - bx.y, 0.f);
      float iou = inter / (iar + jar - inter + 1e-12f);
      if (iou > TH) bits |= (1ull << u);       // strict > (f32 0.3)
    }
  }
  // transpose: word for target u = ballot over source lanes of bit u
  uint64_t tw = 0;
#pragma unroll
  for (int u = 0; u < 64; ++u) {
    uint64_t bal = __ballot((bits >> u) & 1ull);
    if (t == u) tw = bal;
  }
  tmask[((size_t)b * NBLK + tbk) * KROW + (size_t)(sbk * 64 + t)] = tw;
}

// ---------------- stage 4+5: Jacobi fixpoint NMS + fused top-750 emit ----------------
// Rounds 4-8 lesson: the 79-chunk sequential scan floors at ~8k cyc/chunk (barriers +
// serial closure + 4-wave TLP). Greedy NMS is the unique fixpoint of
//   keep[j] = valid[j] & !OR_{i<j}(keep[i] & M[i][j])
// (deps strictly i<j => DAG => unique). Jacobi iteration converges in (chain depth)
// iterations (~5-10 for random boxes) and each iteration is EMBARRASSINGLY parallel:
// 16 waves x coalesced 512B loads, no serial closure, 3 barriers/iter total.
// Consecutive-bitmap equality == fixpoint == exact greedy result.
__global__ __launch_bounds__(1024) void nms_fix_emit(const uint64_t* __restrict__ tmask,
                                                     const float* __restrict__ tscore,
                                                     const float* __restrict__ dets,
                                                     float* __restrict__ out, int B) {
  __shared__ uint64_t s_keep[2][80];
  __shared__ int s_changed;
  __shared__ int s_pref[NBLK + 1];
  int b = blockIdx.x;
  int tid = threadIdx.x;
  int wid = tid >> 6, lane = tid & 63;
  const uint64_t* mb = tmask + (size_t)b * NBLK * KROW;
  const float* sb = tscore + (size_t)b * TOPK;

  // each thread owns targets j = tid + q*1024, q=0..4 (covers 5120 >= 5056 padded)
  float sc[5];
  bool val[5];
#pragma unroll
  for (int q = 0; q < 5; ++q) {
    int j = tid + q * 1024;
    sc[q] = (j < TOPK) ? sb[j] : -1.0f;
    val[q] = (j < TOPK) && (sc[q] > TH);
  }
  // init keep = valid (wave-uniform chunk per (wid,q): ch = wid + q*16)
#pragma unroll
  for (int q = 0; q < 5; ++q) {
    uint64_t w = __ballot(val[q]);
    int ch = wid + q * 16;
    if (ch < NBLK && lane == 0) s_keep[0][ch] = w;
  }

  int cur = 0;
  for (;;) {
    __syncthreads();                      // keep[cur] writes visible; all aligned
    if (tid == 0) s_changed = 0;
    __syncthreads();
    const uint64_t* kp = s_keep[cur];
#pragma unroll
    for (int q = 0; q < 5; ++q) {
      int j = tid + q * 1024;
      int tc = j >> 6;                    // wave-uniform
      uint64_t sup = 0;
      if (tc < NBLK) {
        const uint64_t* row = mb + (size_t)tc * KROW + lane;  // j&63 == lane
        uint64_t a0 = 0, a1 = 0, a2 = 0, a3 = 0;
        int nw = tc + 1, w = 0;
        for (; w + 4 <= nw; w += 4) {     // 4 independent loads in flight
          uint64_t m0 = row[(w + 0) * 64], m1 = row[(w + 1) * 64];
          uint64_t m2 = row[(w + 2) * 64], m3 = row[(w + 3) * 64];
          a0 |= m0 & kp[w + 0]; a1 |= m1 & kp[w + 1];
          a2 |= m2 & kp[w + 2]; a3 |= m3 & kp[w + 3];
        }
        for (; w < nw; ++w) a0 |= row[w * 64] & kp[w];
        sup = (a0 | a1) | (a2 | a3);
      }
      uint64_t nk = __ballot(val[q] && sup == 0);
      int ch = wid + q * 16;
      if (ch < NBLK && lane == 0) {
        s_keep[cur ^ 1][ch] = nk;
        if (nk != kp[ch]) s_changed = 1;  // benign race: all writers store 1
      }
    }
    __syncthreads();                      // all chunk words + s_changed final
    if (!s_changed) break;                // uniform decision; fixpoint == greedy
    cur ^= 1;
  }

  // prefix sums of kept counts per chunk
  if (tid == 0) {
    int run = 0;
    for (int cb = 0; cb < NBLK; ++cb) { s_pref[cb] = run; run += __popcll(s_keep[cur][cb]); }
    s_pref[NBLK] = run;
  }
  __syncthreads();
  int K = s_pref[NBLK];

  // top-750 of where(keep, score, -1) == [kept in position order] ++ [not-kept in
  // position order]  (tscore already desc with index-asc ties; -1 ties -> index asc)
  for (int cb = wid; cb < NBLK; cb += 16) {
    int p = cb * 64 + lane;
    if (p >= TOPK) continue;
    uint64_t aw = s_keep[cur][cb];
    int kept = (int)((aw >> lane) & 1ull);
    int within = __popcll(aw & ((1ull << lane) - 1ull));
    int rank = s_pref[cb] + within;                          // kept rank
    int slot = kept ? rank : (K + (p - s_pref[cb] - within)); // filler after all kept
    if (slot < KEEPK) {
      const float* d = dets + ((size_t)b * TOPK + p) * 16;
      float* o = out + ((size_t)b * KEEPK + slot) * 15;
#pragma unroll
      for (int ccol = 0; ccol < 15; ++ccol) o[ccol] = d[ccol];
      out[(size_t)B * KEEPK * 15 + (size_t)b * KEEPK + slot] = kept ? 1.0f : 0.0f;
    }
  }
}

extern "C" void kernel_launch(void* const* d_in, const int* in_sizes, int n_in,
                              void* d_out, int out_size, void* d_ws, size_t ws_size,
                              hipStream_t stream) {
  const float* cls    = (const float*)d_in[0];
  const float* obj    = (const float*)d_in[1];
  const float* bbox   = (const float*)d_in[2];
  const float* kps    = (const float*)d_in[3];
  const float* priors = (const float*)d_in[4];
  int N = in_sizes[4] / 4;
  int B = in_sizes[0] / N;
  if (N > MPAD) return;

  char* ws = (char*)d_ws;
  size_t off = 0;
  auto alloc = [&](size_t bytes) -> void* {
    void* p = ws + off;
    off += (bytes + 255) & ~(size_t)255;
    return p;
  };
  uint64_t* keys1  = (uint64_t*)alloc((size_t)B * MPAD * 8);
  float*    dets   = (float*)   alloc((size_t)B * TOPK * 16 * 4);
  float*    tscore = (float*)   alloc((size_t)B * TOPK * 4 + 4096);
  uint64_t* tmask  = (uint64_t*)alloc((size_t)B * NBLK * KROW * 8 + 4096);
  if (off > ws_size) return;  // fail visibly rather than corrupt
  // merge buffers alias tmask (lifetimes disjoint: sort completes before nms_mask)
  uint64_t* keys2 = tmask;                       // B * 4 * 8192
  uint64_t* keys3 = keys2 + (size_t)B * 4 * 8192;
  uint64_t* keys4 = keys3 + (size_t)B * 2 * 8192;

  build_keys<<<dim3((MPAD + 255) / 256, B), 256, 0, stream>>>(cls, obj, keys1, N);
  bitonic_local_full<<<dim3(MPAD / 8192, B), 1024, 0, stream>>>(keys1);
  merge_prune<<<dim3(4, B), 1024, 0, stream>>>(keys1, keys2);
  merge_prune<<<dim3(2, B), 1024, 0, stream>>>(keys2, keys3);
  merge_prune<<<dim3(1, B), 1024, 0, stream>>>(keys3, keys4);
  gather_decode<<<dim3((TOPK + 255) / 256, B), 256, 0, stream>>>(keys4, bbox, kps, priors,
                                                                 dets, tscore, N);
  nms_mask<<<dim3(NBLK, NBLK, B), 64, 0, stream>>>(dets, tmask);
  nms_fix_emit<<<B, 1024, 0, stream>>>(tmask, tscore, dets, (float*)d_out, B);
}

// Round 10
// 329.902 us; speedup vs baseline: 1.9069x; 1.1443x over previous
//
#include <hip/hip_runtime.h>
#include <stdint.h>

#pragma clang fp contract(off)   // match numpy: no FMA fusion in decode/IoU math

static constexpr int TOPK  = 5000;
static constexpr int KEEPK = 750;
static constexpr int MPAD  = 65536;   // >= N (33600), power of 2
static constexpr int NBLK  = (TOPK + 63) / 64;   // 79
static constexpr int NPAIR = NBLK * (NBLK + 1) / 2;  // 3160 triangular tile pairs
static constexpr int KROW  = NBLK * 64;          // 5056 (padded mask row)
static constexpr float TH  = 0.3f;    // strict '>' everywhere (f32 weak-typed 0.3)

__device__ __forceinline__ uint32_t key_of(float f) {
  uint32_t u = __float_as_uint(f);
  u = (u & 0x80000000u) ? ~u : (u | 0x80000000u);  // ascending-ordered uint
  return ~u;                                        // ascending key == descending float
}
__device__ __forceinline__ float val_of(uint32_t key) {
  uint32_t u = ~key;
  return (u & 0x80000000u) ? __uint_as_float(u ^ 0x80000000u) : __uint_as_float(~u);
}

// ---------------- stage 1: composite keys (score desc, index asc) ----------------
__global__ void build_keys(const float* __restrict__ cls, const float* __restrict__ obj,
                           uint64_t* __restrict__ keys, int N) {
  int b = blockIdx.y;
  int i = blockIdx.x * blockDim.x + threadIdx.x;
  if (i >= MPAD) return;
  uint64_t c = ~0ull;
  if (i < N) {
    size_t o = (size_t)b * N + i;
    float s = sqrtf(cls[o] * obj[o]);          // mul+sqrt: bit-exact vs np
    float m = (s > TH) ? s : -1.0f;            // strict > (jax weak-typed f32 0.3)
    c = ((uint64_t)key_of(m) << 32) | (uint32_t)i;
  }
  keys[(size_t)b * MPAD + i] = c;
}

// ---------------- local bitonic: sorts each 8192-chunk, alternating asc/desc ----------------
__global__ __launch_bounds__(1024) void bitonic_local_full(uint64_t* __restrict__ keys) {
  __shared__ uint64_t sh[8192];
  int base = blockIdx.x * 8192;
  uint64_t* a = keys + (size_t)blockIdx.y * MPAD + base;
  for (int t = threadIdx.x; t < 8192; t += 1024) sh[t] = a[t];
  __syncthreads();
  for (int k = 2; k <= 8192; k <<= 1) {
    for (int j = k >> 1; j > 0; j >>= 1) {
      for (int t = threadIdx.x; t < 4096; t += 1024) {
        int i = ((t & ~(j - 1)) << 1) | (t & (j - 1));
        int l = i | j;
        bool asc = (((base + i) & k) == 0);
        uint64_t x = sh[i], y = sh[l];
        if ((x > y) == asc) { sh[i] = y; sh[l] = x; }
      }
      __syncthreads();
    }
  }
  for (int t = threadIdx.x; t < 8192; t += 1024) a[t] = sh[t];
}

// ---------------- merge-prune: keep smallest 8192 of (asc, desc) chunk pair ----------------
__global__ __launch_bounds__(1024) void merge_prune(const uint64_t* __restrict__ src,
                                                    uint64_t* __restrict__ dst) {
  __shared__ uint64_t sh[8192];
  int m = blockIdx.x, b = blockIdx.y;
  const uint64_t* A  = src + ((size_t)b * gridDim.x * 2 + 2 * m) * 8192;
  const uint64_t* Bp = A + 8192;
  for (int t = threadIdx.x; t < 8192; t += 1024) {
    uint64_t x = A[t], y = Bp[t];
    sh[t] = x < y ? x : y;
  }
  __syncthreads();
  bool asc = ((m & 1) == 0);
  for (int j = 4096; j > 0; j >>= 1) {
    for (int t = threadIdx.x; t < 4096; t += 1024) {
      int i = ((t & ~(j - 1)) << 1) | (t & (j - 1));
      int l = i | j;
      uint64_t x = sh[i], y = sh[l];
      if ((x > y) == asc) { sh[i] = y; sh[l] = x; }
    }
    __syncthreads();
  }
  uint64_t* D = dst + ((size_t)b * gridDim.x + m) * 8192;
  for (int t = threadIdx.x; t < 8192; t += 1024) D[t] = sh[t];
}

// ---------------- stage 2: gather top-5000, decode boxes+kps (+areas) ----------------
__global__ void gather_decode(const uint64_t* __restrict__ keys,
                              const float* __restrict__ bbox, const float* __restrict__ kps,
                              const float* __restrict__ priors,
                              float* __restrict__ dets, float* __restrict__ tscore,
                              float* __restrict__ areas, int N) {
  int b = blockIdx.y;
  int r = blockIdx.x * blockDim.x + threadIdx.x;
  if (r >= TOPK) return;
  uint64_t c = keys[(size_t)b * 8192 + r];
  uint32_t idx = (uint32_t)c;
  float score = val_of((uint32_t)(c >> 32));
  float4 pr = ((const float4*)priors)[idx];
  const float* bb = bbox + ((size_t)b * N + idx) * 4;
  float cx = pr.x + bb[0] * pr.z;
  float cy = pr.y + bb[1] * pr.w;
  float w = pr.z * expf(bb[2]);
  float h = pr.w * expf(bb[3]);
  float x1 = cx - w * 0.5f, y1 = cy - h * 0.5f;
  float x2 = x1 + w, y2 = y1 + h;
  float* d = dets + ((size_t)b * TOPK + r) * 16;
  d[0] = x1; d[1] = y1; d[2] = x2; d[3] = y2;
  // area exactly as np: max(x2-x1,0)*max(y2-y1,0) on the ROUNDED coords
  areas[(size_t)b * TOPK + r] = fmaxf(x2 - x1, 0.0f) * fmaxf(y2 - y1, 0.0f);
  const float* kp = kps + ((size_t)b * N + idx) * 10;
#pragma unroll
  for (int q = 0; q < 5; ++q) {
    d[4 + 2 * q] = pr.x + kp[2 * q] * pr.z;
    d[5 + 2 * q] = pr.y + kp[2 * q + 1] * pr.w;
  }
  d[14] = score;
  tscore[(size_t)b * TOPK + r] = score;
}

// ---------------- stage 3: NMS bitmask, target-major DIRECT (no transpose) ----------------
// Round-9 lesson: nms_mask is VALU-bound (VALUBusy~100%). Cuts: (1) lane = TARGET so
// the word tmask[(b,tbk)][sbk*64+lane] is built directly -- the 64-ballot transpose
// (~300 instr/block) is gone; (2) IEEE division replaced by multiply-compare with an
// exact rare fallback: |inter-0.3*denom| <= 6e-7*rhs (~5ulp, covers both rounding
// chains) recomputes via true division -- bitwise-identical decisions to np;
// (3) per-item areas precomputed; (4) only triangular (sbk<=tbk) blocks launched.
__global__ __launch_bounds__(64) void nms_mask(const float* __restrict__ dets,
                                               const float* __restrict__ areas,
                                               uint64_t* __restrict__ tmask) {
  int pid = blockIdx.x, b = blockIdx.y;
  int tbk = (int)((sqrtf(8.0f * (float)pid + 1.0f) - 1.0f) * 0.5f);
  while (((tbk + 1) * (tbk + 2)) / 2 <= pid) ++tbk;   // decode pid -> (sbk, tbk)
  while ((tbk * (tbk + 1)) / 2 > pid) --tbk;
  int sbk = pid - (tbk * (tbk + 1)) / 2;

  __shared__ float4 sbox[64];
  __shared__ float sarea[64];
  int t = threadIdx.x;
  {
    int i = min(sbk * 64 + t, TOPK - 1);              // clamp: pad rows masked downstream
    const float* di = dets + ((size_t)b * TOPK + i) * 16;
    sbox[t] = make_float4(di[0], di[1], di[2], di[3]);
    sarea[t] = areas[(size_t)b * TOPK + i];
  }
  __syncthreads();

  int jc = min(tbk * 64 + t, TOPK - 1);               // this lane's target
  const float* dj = dets + ((size_t)b * TOPK + jc) * 16;
  float jx1 = dj[0], jy1 = dj[1], jx2 = dj[2], jy2 = dj[3];
  float ja = areas[(size_t)b * TOPK + jc];

  uint64_t tw = 0, unc = 0;
#pragma unroll
  for (int u = 0; u < 64; ++u) {
    float4 bx = sbox[u];
    float xx1 = fmaxf(jx1, bx.x), yy1 = fmaxf(jy1, bx.y);
    float xx2 = fminf(jx2, bx.z), yy2 = fminf(jy2, bx.w);
    float ww = fmaxf(xx2 - xx1, 0.f), hh = fmaxf(yy2 - yy1, 0.f);
    float inter = ww * hh;
    float denom = sarea[u] + ja - inter + 1e-12f;     // same assoc order as np
    float rhs = TH * denom;
    tw  |= (uint64_t)(inter > rhs) << u;
    unc |= (uint64_t)(fabsf(inter - rhs) <= 6e-7f * rhs) << u;
  }
  // rare exact fallback: redo borderline pairs with the true IEEE divide
  if (unc) {
    do {
      int u = __ffsll((unsigned long long)unc) - 1;
      float4 bx = sbox[u];
      float xx1 = fmaxf(jx1, bx.x), yy1 = fmaxf(jy1, bx.y);
      float xx2 = fminf(jx2, bx.z), yy2 = fminf(jy2, bx.w);
      float ww = fmaxf(xx2 - xx1, 0.f), hh = fmaxf(yy2 - yy1, 0.f);
      float inter = ww * hh;
      float denom = sarea[u] + ja - inter + 1e-12f;
      uint64_t bit = 1ull << u;
      tw = (tw & ~bit) | ((inter / denom > TH) ? bit : 0ull);
      unc &= unc - 1;
    } while (unc);
  }
  if (sbk == tbk) tw &= (t == 0) ? 0ull : ((1ull << t) - 1ull);  // strict i<j in-tile
  tmask[((size_t)b * NBLK + tbk) * KROW + (size_t)(sbk * 64 + t)] = tw;
}

// ---------------- stage 4+5: Jacobi fixpoint NMS + fused top-750 emit ----------------
// Greedy NMS == unique fixpoint of keep[j] = valid[j] & !OR_{i<j}(keep[i] & M[i][j]).
// Jacobi-iterate (converges in chain-depth iters, ~5-10); each iteration is fully
// parallel: 16 waves x coalesced loads. Bitmap equality == fixpoint == exact greedy.
__global__ __launch_bounds__(1024) void nms_fix_emit(const uint64_t* __restrict__ tmask,
                                                     const float* __restrict__ tscore,
                                                     const float* __restrict__ dets,
                                                     float* __restrict__ out, int B) {
  __shared__ uint64_t s_keep[2][80];
  __shared__ int s_changed;
  __shared__ int s_pref[NBLK + 1];
  int b = blockIdx.x;
  int tid = threadIdx.x;
  int wid = tid >> 6, lane = tid & 63;
  const uint64_t* mb = tmask + (size_t)b * NBLK * KROW;
  const float* sb = tscore + (size_t)b * TOPK;

  float sc[5];
  bool val[5];
#pragma unroll
  for (int q = 0; q < 5; ++q) {
    int j = tid + q * 1024;
    sc[q] = (j < TOPK) ? sb[j] : -1.0f;
    val[q] = (j < TOPK) && (sc[q] > TH);
  }
#pragma unroll
  for (int q = 0; q < 5; ++q) {
    uint64_t w = __ballot(val[q]);
    int ch = wid + q * 16;
    if (ch < NBLK && lane == 0) s_keep[0][ch] = w;
  }

  int cur = 0;
  for (;;) {
    __syncthreads();
    if (tid == 0) s_changed = 0;
    __syncthreads();
    const uint64_t* kp = s_keep[cur];
#pragma unroll
    for (int q = 0; q < 5; ++q) {
      int j = tid + q * 1024;
      int tc = j >> 6;                    // wave-uniform
      uint64_t sup = 0;
      if (tc < NBLK) {
        const uint64_t* row = mb + (size_t)tc * KROW + lane;  // j&63 == lane
        uint64_t a0 = 0, a1 = 0, a2 = 0, a3 = 0;
        int nw = tc + 1, w = 0;
        for (; w + 4 <= nw; w += 4) {     // 4 independent loads in flight
          uint64_t m0 = row[(w + 0) * 64], m1 = row[(w + 1) * 64];
          uint64_t m2 = row[(w + 2) * 64], m3 = row[(w + 3) * 64];
          a0 |= m0 & kp[w + 0]; a1 |= m1 & kp[w + 1];
          a2 |= m2 & kp[w + 2]; a3 |= m3 & kp[w + 3];
        }
        for (; w < nw; ++w) a0 |= row[w * 64] & kp[w];
        sup = (a0 | a1) | (a2 | a3);
      }
      uint64_t nk = __ballot(val[q] && sup == 0);
      int ch = wid + q * 16;
      if (ch < NBLK && lane == 0) {
        s_keep[cur ^ 1][ch] = nk;
        if (nk != kp[ch]) s_changed = 1;  // benign race: all writers store 1
      }
    }
    __syncthreads();
    if (!s_changed) break;                // uniform; fixpoint == greedy
    cur ^= 1;
  }

  if (tid == 0) {
    int run = 0;
    for (int cb = 0; cb < NBLK; ++cb) { s_pref[cb] = run; run += __popcll(s_keep[cur][cb]); }
    s_pref[NBLK] = run;
  }
  __syncthreads();
  int K = s_pref[NBLK];

  // top-750 of where(keep, score, -1) == [kept in position order] ++ [not-kept in
  // position order]  (tscore already desc with index-asc ties; -1 ties -> index asc)
  for (int cb = wid; cb < NBLK; cb += 16) {
    int p = cb * 64 + lane;
    if (p >= TOPK) continue;
    uint64_t aw = s_keep[cur][cb];
    int kept = (int)((aw >> lane) & 1ull);
    int within = __popcll(aw & ((1ull << lane) - 1ull));
    int rank = s_pref[cb] + within;
    int slot = kept ? rank : (K + (p - s_pref[cb] - within));
    if (slot < KEEPK) {
      const float* d = dets + ((size_t)b * TOPK + p) * 16;
      float* o = out + ((size_t)b * KEEPK + slot) * 15;
#pragma unroll
      for (int ccol = 0; ccol < 15; ++ccol) o[ccol] = d[ccol];
      out[(size_t)B * KEEPK * 15 + (size_t)b * KEEPK + slot] = kept ? 1.0f : 0.0f;
    }
  }
}

extern "C" void kernel_launch(void* const* d_in, const int* in_sizes, int n_in,
                              void* d_out, int out_size, void* d_ws, size_t ws_size,
                              hipStream_t stream) {
  const float* cls    = (const float*)d_in[0];
  const float* obj    = (const float*)d_in[1];
  const float* bbox   = (const float*)d_in[2];
  const float* kps    = (const float*)d_in[3];
  const float* priors = (const float*)d_in[4];
  int N = in_sizes[4] / 4;
  int B = in_sizes[0] / N;
  if (N > MPAD) return;

  char* ws = (char*)d_ws;
  size_t off = 0;
  auto alloc = [&](size_t bytes) -> void* {
    void* p = ws + off;
    off += (bytes + 255) & ~(size_t)255;
    return p;
  };
  uint64_t* keys1  = (uint64_t*)alloc((size_t)B * MPAD * 8);
  float*    dets   = (float*)   alloc((size_t)B * TOPK * 16 * 4);
  float*    tscore = (float*)   alloc((size_t)B * TOPK * 4 + 4096);
  float*    areas  = (float*)   alloc((size_t)B * TOPK * 4 + 4096);
  uint64_t* tmask  = (uint64_t*)alloc((size_t)B * NBLK * KROW * 8 + 4096);
  if (off > ws_size) return;  // fail visibly rather than corrupt
  // merge buffers alias tmask (lifetimes disjoint: sort completes before nms_mask)
  uint64_t* keys2 = tmask;                       // B * 4 * 8192
  uint64_t* keys3 = keys2 + (size_t)B * 4 * 8192;
  uint64_t* keys4 = keys3 + (size_t)B * 2 * 8192;

  build_keys<<<dim3((MPAD + 255) / 256, B), 256, 0, stream>>>(cls, obj, keys1, N);
  bitonic_local_full<<<dim3(MPAD / 8192, B), 1024, 0, stream>>>(keys1);
  merge_prune<<<dim3(4, B), 1024, 0, stream>>>(keys1, keys2);
  merge_prune<<<dim3(2, B), 1024, 0, stream>>>(keys2, keys3);
  merge_prune<<<dim3(1, B), 1024, 0, stream>>>(keys3, keys4);
  gather_decode<<<dim3((TOPK + 255) / 256, B), 256, 0, stream>>>(keys4, bbox, kps, priors,
                                                                 dets, tscore, areas, N);
  nms_mask<<<dim3(NPAIR, B), 64, 0, stream>>>(dets, areas, tmask);
  nms_fix_emit<<<B, 1024, 0, stream>>>(tmask, tscore, dets, (float*)d_out, B);
}